// Round 3
// baseline (303.761 us; speedup 1.0000x reference)
//
#include <hip/hip_runtime.h>

// Tensor Fusion Network, MI355X. Round 3.
// k1: fusion[b][p] bf16 (p = ij*97+k) via per-wave MFMA, barrier-free main loop.
// k2: split-K GEMM, barrier-free + LDS-free: MFMA frags built directly from
//     global (A: dwordx4 from fusion; B: coalesced scalar W1 loads + cvt).
// k3: parallel reduce + bias + relu. k45: fused MLP tail.

#define B_    128
#define T_    64
#define A1    49
#define V1    49
#define X1    97
#define IJ    2401      // 49*49
#define KTOT  232897    // IJ*97
#define FP    232928    // KTOT padded to multiple of 32
#define PF    128
#define KC    256       // K-chunk per k2 block
#define NB2   910       // ceil(FP/KC)

typedef short s8v __attribute__((ext_vector_type(8)));   // 8 bf16
typedef float f4v __attribute__((ext_vector_type(4)));   // 4 fp32

__device__ __forceinline__ unsigned short f2bf(float f) {
    union { float f; unsigned u; } v; v.f = f;
    return (unsigned short)((v.u + 0x7FFFu + ((v.u >> 16) & 1u)) >> 16); // RNE
}

// ---------------- k1: fusion (bf16) -------------------------------------
// grid (4, 128): blockIdx.y = b, blockIdx.x covers 38 ij-tiles of 16 (151 total).
// 512 threads = 8 waves; each wave owns a private w-slice in LDS -> no barriers
// after initial staging.
__global__ __launch_bounds__(512) void k1_fusion(
    const float* __restrict__ audio, const float* __restrict__ video,
    const float* __restrict__ text, unsigned short* __restrict__ fusion)
{
    __shared__ float a_s[T_ * A1];                 // [t][i]
    __shared__ float v_s[T_ * V1];                 // [t][j]
    __shared__ unsigned short xT[112 * 72];        // [k][t], rows padded to 72
    __shared__ unsigned short w_ws[8][16 * 72];    // per-wave [ij_local][t]

    const int b = blockIdx.y;
    const int bx = blockIdx.x;
    const int tid = threadIdx.x;

    for (int idx = tid; idx < T_ * A1; idx += 512) {
        int t = idx / 49, i = idx - t * 49;
        a_s[idx] = (i == 0) ? 1.0f : audio[(b * T_ + t) * 48 + (i - 1)];
        v_s[idx] = (i == 0) ? 1.0f : video[(b * T_ + t) * 48 + (i - 1)];
    }
    for (int idx = tid; idx < T_ * X1; idx += 512) {
        int t = idx / 97, k = idx - t * 97;
        xT[k * 72 + t] = f2bf((k == 0) ? 1.0f : text[(b * T_ + t) * 96 + (k - 1)]);
    }
    for (int idx = tid; idx < 15 * 64; idx += 512) {   // zero pad rows k=97..111
        xT[(97 + (idx >> 6)) * 72 + (idx & 63)] = 0;
    }
    __syncthreads();

    const int wave = tid >> 6, lane = tid & 63;
    const int q = lane >> 4, ln = lane & 15;
    unsigned short* w_s = w_ws[wave];

    for (int it = 0; it < 5; ++it) {
        const int tw = it * 8 + wave;          // tile-within-x-block
        if (tw >= 38) break;                   // wave-uniform
        const int tl = bx * 38 + tw;           // global 16-ij tile
        if (tl >= 151) break;
        const int ij0 = tl * 16;

        #pragma unroll
        for (int ijl = 0; ijl < 16; ++ijl) {
            int ij = ij0 + ijl;
            unsigned short wv = 0;
            if (ij < IJ) {
                int i = ij / 49, j = ij - i * 49;
                wv = f2bf(a_s[lane * 49 + i] * v_s[lane * 49 + j]);
            }
            w_s[ijl * 72 + lane] = wv;
        }
        s8v af0 = *(const s8v*)&w_s[ln * 72 + q * 8];
        s8v af1 = *(const s8v*)&w_s[ln * 72 + 32 + q * 8];
        #pragma unroll
        for (int nt = 0; nt < 7; ++nt) {
            s8v bf0 = *(const s8v*)&xT[(nt * 16 + ln) * 72 + q * 8];
            s8v bf1 = *(const s8v*)&xT[(nt * 16 + ln) * 72 + 32 + q * 8];
            f4v acc = {0.f, 0.f, 0.f, 0.f};
            acc = __builtin_amdgcn_mfma_f32_16x16x32_bf16(af0, bf0, acc, 0, 0, 0);
            acc = __builtin_amdgcn_mfma_f32_16x16x32_bf16(af1, bf1, acc, 0, 0, 0);
            int kk = nt * 16 + ln;             // C: col=ln -> k, row=q*4+r -> ij
            if (kk < X1) {
                #pragma unroll
                for (int r = 0; r < 4; ++r) {
                    int ij = ij0 + q * 4 + r;
                    if (ij < IJ)
                        fusion[(size_t)b * FP + ij * X1 + kk] = f2bf(acc[r]);
                }
            }
        }
    }
}

// ---------------- k2: split-K GEMM, barrier/LDS-free --------------------
// 910 blocks x 512 thr (8 waves). Wave owns f-tile = wave*16; covers all
// M=128 (8 m-tiles). Per K-step(32): 1 B-frag (W1 scalar loads + cvt),
// 8 A-frags (dwordx4 from fusion), 8 MFMA. No __syncthreads anywhere.
template<bool TAIL>
__device__ __forceinline__ void k2_body(
    const unsigned short* __restrict__ fusion, const float* __restrict__ W1,
    float* __restrict__ partials, int blk)
{
    const int kbase = blk * KC;
    const int tid = threadIdx.x;
    const int wave = tid >> 6, lane = tid & 63;
    const int q = lane >> 4, ln = lane & 15;
    const int f = wave * 16 + ln;

    f4v acc[8];
    #pragma unroll
    for (int m = 0; m < 8; ++m) acc[m] = (f4v){0.f, 0.f, 0.f, 0.f};

    #pragma unroll 2
    for (int s = 0; s < 8; ++s) {
        const int p0 = kbase + s * 32;
        s8v bfrag;
        #pragma unroll
        for (int j = 0; j < 8; ++j) {
            int p = p0 + q * 8 + j;
            float w;
            if (TAIL)
                w = (p < KTOT) ? W1[(size_t)p * PF + f] : 0.f;
            else
                w = __builtin_nontemporal_load(&W1[(size_t)p * PF + f]);
            ((unsigned short*)&bfrag)[j] = f2bf(w);
        }
        #pragma unroll
        for (int m = 0; m < 8; ++m) {
            s8v afrag = *(const s8v*)&fusion[(size_t)(m * 16 + ln) * FP + p0 + q * 8];
            acc[m] = __builtin_amdgcn_mfma_f32_16x16x32_bf16(afrag, bfrag, acc[m], 0, 0, 0);
        }
    }

    float* outp = partials + (size_t)blk * 16384;
    #pragma unroll
    for (int m = 0; m < 8; ++m) {
        #pragma unroll
        for (int r = 0; r < 4; ++r)
            outp[(m * 16 + q * 4 + r) * 128 + f] = acc[m][r];
    }
}

__global__ __launch_bounds__(512) void k2_gemm(
    const unsigned short* __restrict__ fusion, const float* __restrict__ W1,
    float* __restrict__ partials)
{
    const int blk = blockIdx.x;
    if (blk == NB2 - 1) k2_body<true>(fusion, W1, partials, blk);
    else                k2_body<false>(fusion, W1, partials, blk);
}

// ---------------- k3: reduce partials + bias + relu ---------------------
// 512 blocks x 256 thr: block owns 32 e-values, 8-way r-split per e.
__global__ __launch_bounds__(256) void k3_reduce(
    const float* __restrict__ partials, const float* __restrict__ b1,
    float* __restrict__ h1)
{
    __shared__ float red[256];
    const int e = blockIdx.x * 32 + (threadIdx.x & 31);
    const int rh = threadIdx.x >> 5;           // 0..7
    float s0 = 0.f, s1 = 0.f;
    int r = rh;
    for (; r + 8 < NB2; r += 16) {
        s0 += partials[(size_t)r * 16384 + e];
        s1 += partials[(size_t)(r + 8) * 16384 + e];
    }
    for (; r < NB2; r += 8) s0 += partials[(size_t)r * 16384 + e];
    red[threadIdx.x] = s0 + s1;
    __syncthreads();
    if (threadIdx.x < 32) {
        float v = 0.f;
        #pragma unroll
        for (int g = 0; g < 8; ++g) v += red[g * 32 + threadIdx.x];
        v += b1[e & 127];
        h1[e] = fmaxf(v, 0.f);
    }
}

// ---------------- k45: out = sigmoid(relu(h1@W2+b2)@W3 + b3)*6 - 3 ------
__global__ __launch_bounds__(128) void k45_tail(
    const float* __restrict__ h1, const float* __restrict__ W2,
    const float* __restrict__ b2, const float* __restrict__ W3,
    const float* __restrict__ b3, float* __restrict__ out)
{
    __shared__ float hrow[128];
    __shared__ float h2s[128];
    const int b = blockIdx.x, f = threadIdx.x;
    hrow[f] = h1[b * 128 + f];
    __syncthreads();
    float s = b2[f];
    #pragma unroll 8
    for (int c = 0; c < 128; ++c) s += hrow[c] * W2[c * 128 + f];
    h2s[f] = fmaxf(s, 0.f) * W3[f];
    __syncthreads();
    if (f < 64) {
        float v = h2s[f] + h2s[f + 64];
        #pragma unroll
        for (int off = 32; off > 0; off >>= 1)
            v += __shfl_down(v, off, 64);
        if (f == 0) out[b] = 6.0f / (1.0f + expf(-(v + b3[0]))) - 3.0f;
    }
}

extern "C" void kernel_launch(void* const* d_in, const int* in_sizes, int n_in,
                              void* d_out, int out_size, void* d_ws, size_t ws_size,
                              hipStream_t stream)
{
    const float* audio = (const float*)d_in[0];
    const float* video = (const float*)d_in[1];
    const float* text  = (const float*)d_in[2];
    const float* W1 = (const float*)d_in[3];
    const float* b1 = (const float*)d_in[4];
    const float* W2 = (const float*)d_in[5];
    const float* b2 = (const float*)d_in[6];
    const float* W3 = (const float*)d_in[7];
    const float* b3 = (const float*)d_in[8];
    float* out = (float*)d_out;

    // ws layout (bytes):
    //   fusion bf16 [128][FP]        @ 0          = 59,629,568
    //   partials fp32 [910][16384]   @ 59,629,568 = 59,637,760
    //   h1 fp32 [16384]              @ 119,267,328
    char* ws = (char*)d_ws;
    unsigned short* fusion = (unsigned short*)ws;
    float* partials = (float*)(ws + 59629568);
    float* h1 = (float*)(ws + 119267328);

    k1_fusion<<<dim3(4, 128), 512, 0, stream>>>(audio, video, text, fusion);
    k2_gemm<<<dim3(NB2), 512, 0, stream>>>(fusion, W1, partials);
    k3_reduce<<<dim3(512), 256, 0, stream>>>(partials, b1, h1);
    k45_tail<<<dim3(128), 128, 0, stream>>>(h1, W2, b2, W3, b3, out);
}